// Round 1
// baseline (145.430 us; speedup 1.0000x reference)
//
#include <hip/hip_runtime.h>
#include <hip/hip_bf16.h>
#include <math.h>

#define P 4096          // number of (even,odd) pairs = B/2
#define DIM 128
#define MARGIN_F 1.0f
#define EPS_F 1e-8f

#define BP 64           // tile rows (p)
#define BK 64           // tile cols (k)
#define LDS_STRIDE 132  // 128 + 4 floats pad

typedef float f32x4 __attribute__((ext_vector_type(4)));

// Kernel 1: compute M[p,k] = exp(1 + dot(x[2p], x[2k+1])/128) tile-wise,
// accumulate row sums (over k) into rowsum[p] and column sums (over p) into colsum[k].
__global__ __launch_bounds__(256) void gram_exp_sums(
    const float* __restrict__ x,
    float* __restrict__ rowsum,
    float* __restrict__ colsum) {

    __shared__ float se[BP * LDS_STRIDE];   // even rows tile (row-major)
    __shared__ float so[BK * LDS_STRIDE];   // odd rows tile (row-major)
    __shared__ float red_r[BP];
    __shared__ float red_c[BK];

    const int tid = threadIdx.x;
    const int tx = tid & 15;   // col-group: cols {tx, tx+16, tx+32, tx+48}
    const int ty = tid >> 4;   // row-group: rows {4ty .. 4ty+3}
    const int p0 = blockIdx.y * BP;
    const int k0 = blockIdx.x * BK;

    if (tid < BP) red_r[tid] = 0.0f;
    if (tid < BK) red_c[tid] = 0.0f;

    // Load even-row tile: rows 2*(p0+r), coalesced float4
    for (int i = tid; i < BP * 32; i += 256) {
        int r = i >> 5, c4 = i & 31;
        f32x4 v = *reinterpret_cast<const f32x4*>(
            x + (size_t)(2 * (p0 + r)) * DIM + c4 * 4);
        *reinterpret_cast<f32x4*>(&se[r * LDS_STRIDE + c4 * 4]) = v;
    }
    // Load odd-row tile: rows 2*(k0+r)+1
    for (int i = tid; i < BK * 32; i += 256) {
        int r = i >> 5, c4 = i & 31;
        f32x4 v = *reinterpret_cast<const f32x4*>(
            x + (size_t)(2 * (k0 + r) + 1) * DIM + c4 * 4);
        *reinterpret_cast<f32x4*>(&so[r * LDS_STRIDE + c4 * 4]) = v;
    }
    __syncthreads();

    float acc[4][4];
    #pragma unroll
    for (int j = 0; j < 4; ++j)
        #pragma unroll
        for (int c = 0; c < 4; ++c) acc[j][c] = 0.0f;

    // K loop in chunks of 4 floats (float4 LDS reads)
    #pragma unroll 4
    for (int kk4 = 0; kk4 < DIM / 4; ++kk4) {
        f32x4 a[4], b[4];
        #pragma unroll
        for (int j = 0; j < 4; ++j)
            a[j] = *reinterpret_cast<const f32x4*>(
                &se[(ty * 4 + j) * LDS_STRIDE + kk4 * 4]);
        #pragma unroll
        for (int c = 0; c < 4; ++c)
            b[c] = *reinterpret_cast<const f32x4*>(
                &so[(tx + 16 * c) * LDS_STRIDE + kk4 * 4]);
        #pragma unroll
        for (int j = 0; j < 4; ++j)
            #pragma unroll
            for (int c = 0; c < 4; ++c)
                acc[j][c] += a[j][0] * b[c][0] + a[j][1] * b[c][1]
                           + a[j][2] * b[c][2] + a[j][3] * b[c][3];
    }

    // exp epilogue + per-thread row/col partials
    float rsum[4] = {0.f, 0.f, 0.f, 0.f};
    float csum[4] = {0.f, 0.f, 0.f, 0.f};
    #pragma unroll
    for (int j = 0; j < 4; ++j)
        #pragma unroll
        for (int c = 0; c < 4; ++c) {
            float m = __expf(MARGIN_F + acc[j][c] * (1.0f / 128.0f));
            rsum[j] += m;
            csum[c] += m;
        }

    #pragma unroll
    for (int j = 0; j < 4; ++j) atomicAdd(&red_r[ty * 4 + j], rsum[j]);
    #pragma unroll
    for (int c = 0; c < 4; ++c) atomicAdd(&red_c[tx + 16 * c], csum[c]);
    __syncthreads();

    if (tid < BP) atomicAdd(&rowsum[p0 + tid], red_r[tid]);
    if (tid < BK) atomicAdd(&colsum[k0 + tid], red_c[tid]);
}

// Kernel 2: per-p corrections + J + loss reduction.
// neg_ik[p] = rowsum[p] - (2p+1<P ? exp(1+D[2p,4p+3]) : 0)
// neg_jl[p] = colsum[p] - (2p  <P ? exp(1+D[2p+1,4p]) : 0)
// J = log(EPS + neg_ik + neg_jl) - D[2p,2p+1];  loss += relu(J)^2 / B
__global__ __launch_bounds__(256) void finalize(
    const float* __restrict__ x,
    const float* __restrict__ rowsum,
    const float* __restrict__ colsum,
    float* __restrict__ out) {

    __shared__ float wsum[4];
    const int tid = threadIdx.x;
    const int wave = tid >> 6;
    const int lane = tid & 63;
    const int p = blockIdx.x * 4 + wave;   // grid = P/4 -> p in [0,P)

    const float2* xe = reinterpret_cast<const float2*>(x + (size_t)(2 * p) * DIM);
    const float2* xo = reinterpret_cast<const float2*>(x + (size_t)(2 * p + 1) * DIM);
    float2 ve = xe[lane];
    float2 vo = xo[lane];
    float dpos = ve.x * vo.x + ve.y * vo.y;

    float ci = 0.0f, cj = 0.0f;
    if (p < P / 2) {
        const float2* xi = reinterpret_cast<const float2*>(x + (size_t)(4 * p + 3) * DIM);
        const float2* xj = reinterpret_cast<const float2*>(x + (size_t)(4 * p) * DIM);
        float2 vi = xi[lane];
        float2 vj = xj[lane];
        ci = ve.x * vi.x + ve.y * vi.y;   // dot(x[2p],   x[4p+3])
        cj = vo.x * vj.x + vo.y * vj.y;   // dot(x[2p+1], x[4p])
    }

    #pragma unroll
    for (int off = 32; off > 0; off >>= 1) {
        dpos += __shfl_down(dpos, off);
        ci   += __shfl_down(ci, off);
        cj   += __shfl_down(cj, off);
    }

    if (lane == 0) {
        float corr = 0.0f;
        if (p < P / 2)
            corr = __expf(MARGIN_F + ci * (1.0f / 128.0f))
                 + __expf(MARGIN_F + cj * (1.0f / 128.0f));
        float neg = rowsum[p] + colsum[p] - corr;
        float J = logf(EPS_F + neg) - dpos * (1.0f / 128.0f);
        float r = fmaxf(J, 0.0f);
        wsum[wave] = r * r;
    }
    __syncthreads();
    if (tid == 0) {
        float s = (wsum[0] + wsum[1] + wsum[2] + wsum[3]) * (1.0f / 8192.0f);
        atomicAdd(out, s);
    }
}

extern "C" void kernel_launch(void* const* d_in, const int* in_sizes, int n_in,
                              void* d_out, int out_size, void* d_ws, size_t ws_size,
                              hipStream_t stream) {
    const float* x = (const float*)d_in[0];
    float* rowsum = (float*)d_ws;
    float* colsum = rowsum + P;

    hipMemsetAsync(d_ws, 0, 2 * P * sizeof(float), stream);
    hipMemsetAsync(d_out, 0, sizeof(float), stream);

    dim3 grid(P / BK, P / BP);  // (64, 64)
    gram_exp_sums<<<grid, 256, 0, stream>>>(x, rowsum, colsum);
    finalize<<<P / 4, 256, 0, stream>>>(x, rowsum, colsum, (float*)d_out);
}

// Round 2
// 49.937 us; speedup vs baseline: 2.9123x; 2.9123x over previous
//
#include <hip/hip_runtime.h>
#include <hip/hip_bf16.h>
#include <math.h>

#define P 4096          // number of (even,odd) pairs = B/2
#define DIM 128
#define MARGIN_F 1.0f
#define EPS_F 1e-8f
#define BT 128          // output tile (both dims), K = DIM = 128 in one shot

typedef float f32x4 __attribute__((ext_vector_type(4)));
typedef short bf16x8 __attribute__((ext_vector_type(8)));

static __device__ __forceinline__ short f2bf(float f) {
    __hip_bfloat16 h = __float2bfloat16(f);
    return __builtin_bit_cast(short, h);
}

// M[p,k] = exp(1 + dot(x[2p], x[2k+1])/128), accumulated into
// rowsum[p] (sum over k) and colsum[k] (sum over p) without materializing M.
// bf16 MFMA for the Gram product; exp + reduction in-register.
__global__ __launch_bounds__(256) void gram_mfma(
    const float* __restrict__ x,
    float* __restrict__ rowsum,
    float* __restrict__ colsum) {

    // bf16 tiles, XOR-swizzled (short-index ^= (row&7)<<3 == byte ^= (row&7)<<4)
    // to break the 16-way bank conflict of stride-256B fragment reads.
    __shared__ __align__(16) short As[BT * BT];   // A[p_local][k_dim]
    __shared__ __align__(16) short Bs[BT * BT];   // B[k_local][k_dim]

    const int tid = threadIdx.x;
    const int lane = tid & 63;
    const int wave = tid >> 6;
    const int wr = (wave >> 1) * 64;   // wave row origin in tile
    const int wc = (wave & 1) * 64;    // wave col origin in tile
    const int p0 = blockIdx.y * BT;
    const int k0 = blockIdx.x * BT;

    // Stage + convert: 128 rows x 32 float4 per tile, 256 threads -> 16 iters.
    // Global: coalesced float4. LDS: 8B writes, 2-way bank alias (free).
    for (int i = tid; i < BT * 32; i += 256) {
        int r = i >> 5, c4 = i & 31;
        f32x4 va = *reinterpret_cast<const f32x4*>(
            x + (size_t)(2 * (p0 + r)) * DIM + c4 * 4);
        f32x4 vb = *reinterpret_cast<const f32x4*>(
            x + (size_t)(2 * (k0 + r) + 1) * DIM + c4 * 4);
        int idx = (r * 128 + c4 * 4) ^ ((r & 7) << 3);
        short4 pa, pb;
        pa.x = f2bf(va[0]); pa.y = f2bf(va[1]); pa.z = f2bf(va[2]); pa.w = f2bf(va[3]);
        pb.x = f2bf(vb[0]); pb.y = f2bf(vb[1]); pb.z = f2bf(vb[2]); pb.w = f2bf(vb[3]);
        *reinterpret_cast<short4*>(&As[idx]) = pa;
        *reinterpret_cast<short4*>(&Bs[idx]) = pb;
    }
    __syncthreads();

    f32x4 acc[4][4];
    #pragma unroll
    for (int m = 0; m < 4; ++m)
        #pragma unroll
        for (int n = 0; n < 4; ++n)
            acc[m][n] = f32x4{0.f, 0.f, 0.f, 0.f};

    const int lrow = lane & 15;          // A row / B col within fragment
    const int kgrp = (lane >> 4) * 8;    // k base within fragment

    #pragma unroll
    for (int k32 = 0; k32 < 4; ++k32) {
        bf16x8 a[4], b[4];
        #pragma unroll
        for (int m = 0; m < 4; ++m) {
            int rr = wr + m * 16 + lrow;
            int idx = (rr * 128 + k32 * 32 + kgrp) ^ ((rr & 7) << 3);
            a[m] = *reinterpret_cast<const bf16x8*>(&As[idx]);
        }
        #pragma unroll
        for (int n = 0; n < 4; ++n) {
            int cc = wc + n * 16 + lrow;
            int idx = (cc * 128 + k32 * 32 + kgrp) ^ ((cc & 7) << 3);
            b[n] = *reinterpret_cast<const bf16x8*>(&Bs[idx]);
        }
        #pragma unroll
        for (int m = 0; m < 4; ++m)
            #pragma unroll
            for (int n = 0; n < 4; ++n)
                acc[m][n] = __builtin_amdgcn_mfma_f32_16x16x32_bf16(
                    a[m], b[n], acc[m][n], 0, 0, 0);
    }

    // Epilogue. C/D layout (verified m89/m91): col = lane&15, row = (lane>>4)*4 + reg.
    float rs[4][4];   // [m][reg j] row partials (summed over n), per 16-lane group
    float cs[4];      // [n] col partials (summed over m, j)
    #pragma unroll
    for (int m = 0; m < 4; ++m)
        #pragma unroll
        for (int j = 0; j < 4; ++j) rs[m][j] = 0.0f;
    #pragma unroll
    for (int n = 0; n < 4; ++n) cs[n] = 0.0f;

    #pragma unroll
    for (int m = 0; m < 4; ++m)
        #pragma unroll
        for (int n = 0; n < 4; ++n)
            #pragma unroll
            for (int j = 0; j < 4; ++j) {
                float e = __expf(MARGIN_F + acc[m][n][j] * (1.0f / 128.0f));
                rs[m][j] += e;
                cs[n] += e;
            }

    // Row sums: reduce across the 16 lanes of each lane-group (varying col).
    #pragma unroll
    for (int m = 0; m < 4; ++m)
        #pragma unroll
        for (int j = 0; j < 4; ++j) {
            float v = rs[m][j];
            v += __shfl_xor(v, 1);
            v += __shfl_xor(v, 2);
            v += __shfl_xor(v, 4);
            v += __shfl_xor(v, 8);
            rs[m][j] = v;
        }
    if ((lane & 15) == 0) {
        int g = lane >> 4;
        #pragma unroll
        for (int m = 0; m < 4; ++m)
            #pragma unroll
            for (int j = 0; j < 4; ++j)
                atomicAdd(&rowsum[p0 + wr + m * 16 + g * 4 + j], rs[m][j]);
    }

    // Col sums: reduce across the 4 lane-groups (varying row).
    #pragma unroll
    for (int n = 0; n < 4; ++n) {
        float v = cs[n];
        v += __shfl_xor(v, 16);
        v += __shfl_xor(v, 32);
        cs[n] = v;
    }
    if (lane < 16) {
        #pragma unroll
        for (int n = 0; n < 4; ++n)
            atomicAdd(&colsum[k0 + wc + n * 16 + lane], cs[n]);
    }
}

// Per-p corrections + J + loss reduction (fp32 exact — D_pos must not be bf16).
__global__ __launch_bounds__(256) void finalize(
    const float* __restrict__ x,
    const float* __restrict__ rowsum,
    const float* __restrict__ colsum,
    float* __restrict__ out) {

    __shared__ float wsum[4];
    const int tid = threadIdx.x;
    const int wave = tid >> 6;
    const int lane = tid & 63;
    const int p = blockIdx.x * 4 + wave;   // grid = P/4 -> p in [0,P)

    const float2* xe = reinterpret_cast<const float2*>(x + (size_t)(2 * p) * DIM);
    const float2* xo = reinterpret_cast<const float2*>(x + (size_t)(2 * p + 1) * DIM);
    float2 ve = xe[lane];
    float2 vo = xo[lane];
    float dpos = ve.x * vo.x + ve.y * vo.y;

    float ci = 0.0f, cj = 0.0f;
    if (p < P / 2) {
        const float2* xi = reinterpret_cast<const float2*>(x + (size_t)(4 * p + 3) * DIM);
        const float2* xj = reinterpret_cast<const float2*>(x + (size_t)(4 * p) * DIM);
        float2 vi = xi[lane];
        float2 vj = xj[lane];
        ci = ve.x * vi.x + ve.y * vi.y;   // dot(x[2p],   x[4p+3])
        cj = vo.x * vj.x + vo.y * vj.y;   // dot(x[2p+1], x[4p])
    }

    #pragma unroll
    for (int off = 32; off > 0; off >>= 1) {
        dpos += __shfl_down(dpos, off);
        ci   += __shfl_down(ci, off);
        cj   += __shfl_down(cj, off);
    }

    if (lane == 0) {
        float corr = 0.0f;
        if (p < P / 2)
            corr = __expf(MARGIN_F + ci * (1.0f / 128.0f))
                 + __expf(MARGIN_F + cj * (1.0f / 128.0f));
        float neg = rowsum[p] + colsum[p] - corr;
        float J = logf(EPS_F + neg) - dpos * (1.0f / 128.0f);
        float r = fmaxf(J, 0.0f);
        wsum[wave] = r * r;
    }
    __syncthreads();
    if (tid == 0) {
        float s = (wsum[0] + wsum[1] + wsum[2] + wsum[3]) * (1.0f / 8192.0f);
        atomicAdd(out, s);
    }
}

extern "C" void kernel_launch(void* const* d_in, const int* in_sizes, int n_in,
                              void* d_out, int out_size, void* d_ws, size_t ws_size,
                              hipStream_t stream) {
    const float* x = (const float*)d_in[0];
    float* rowsum = (float*)d_ws;
    float* colsum = rowsum + P;

    hipMemsetAsync(d_ws, 0, 2 * P * sizeof(float), stream);
    hipMemsetAsync(d_out, 0, sizeof(float), stream);

    dim3 grid(P / BT, P / BT);  // (32, 32)
    gram_mfma<<<grid, 256, 0, stream>>>(x, rowsum, colsum);
    finalize<<<P / 4, 256, 0, stream>>>(x, rowsum, colsum, (float*)d_out);
}

// Round 3
// 41.980 us; speedup vs baseline: 3.4643x; 1.1895x over previous
//
#include <hip/hip_runtime.h>
#include <hip/hip_bf16.h>
#include <math.h>

#define P 4096          // number of (even,odd) pairs = B/2
#define DIM 128
#define MARGIN_F 1.0f
#define EPS_F 1e-8f
#define BT 128          // gram tile (both dims), K = 128 in one staging

typedef float f32x4 __attribute__((ext_vector_type(4)));
typedef short bf16x8 __attribute__((ext_vector_type(8)));

static __device__ __forceinline__ void gload_lds16(const void* g, void* l) {
    __builtin_amdgcn_global_load_lds(
        (const __attribute__((address_space(1))) void*)g,
        (__attribute__((address_space(3))) void*)l,
        16, 0, 0);
}

// Kernel A: fp32 -> bf16 convert + deinterleave even/odd rows; also zeroes
// rowsum/colsum/out (so no separate memset dispatches needed).
__global__ __launch_bounds__(256) void convert_deint(
    const float* __restrict__ x,
    short* __restrict__ xe,      // [P][DIM] bf16 of even rows
    short* __restrict__ xo,      // [P][DIM] bf16 of odd rows
    float* __restrict__ rowcol,  // 2*P floats to zero
    float* __restrict__ out) {

    const int idx = blockIdx.x * 256 + threadIdx.x;   // 262144 float4s total
    const int row = idx >> 5;      // 32 float4 per row of x
    const int c4 = idx & 31;

    f32x4 v = *reinterpret_cast<const f32x4*>(x + (size_t)idx * 4);
    short4 pk;
    pk.x = __builtin_bit_cast(short, __float2bfloat16(v[0]));
    pk.y = __builtin_bit_cast(short, __float2bfloat16(v[1]));
    pk.z = __builtin_bit_cast(short, __float2bfloat16(v[2]));
    pk.w = __builtin_bit_cast(short, __float2bfloat16(v[3]));
    short* dst = (row & 1) ? xo : xe;
    *reinterpret_cast<short4*>(&dst[(size_t)(row >> 1) * DIM + c4 * 4]) = pk;

    if (idx < 2 * P) rowcol[idx] = 0.0f;
    if (idx == 0) out[0] = 0.0f;
}

// Kernel B: M[p,k] = exp(1 + dot(x[2p], x[2k+1])/128) tile-wise via bf16 MFMA;
// accumulate rowsum[p] (over k) and colsum[k] (over p) without materializing M.
// Staging: global_load_lds w16, linear LDS dest + inverse-XOR-swizzled source;
// fragment reads apply the same XOR (byte ^= (row&7)<<4) -> ~2-way conflicts.
__global__ __launch_bounds__(512, 4) void gram_mfma(
    const short* __restrict__ xe,
    const short* __restrict__ xo,
    float* __restrict__ rowsum,
    float* __restrict__ colsum) {

    __shared__ __align__(16) short As[BT * BT];   // 32 KB
    __shared__ __align__(16) short Bs[BT * BT];   // 32 KB
    __shared__ float red_r[BT];
    __shared__ float red_c[BT];

    const int tid = threadIdx.x;
    const int lane = tid & 63;
    const int wave = tid >> 6;          // 8 waves: 2 row-groups x 4 col-groups
    const int wr = (wave >> 2) * 64;    // wave row origin (64 rows)
    const int wc = (wave & 3) * 32;     // wave col origin (32 cols)
    const int p0 = blockIdx.y * BT;
    const int k0 = blockIdx.x * BT;

    if (tid < BT) red_r[tid] = 0.0f;
    else if (tid < 2 * BT) red_c[tid - BT] = 0.0f;

    // Stage A and B tiles: each tile is a CONTIGUOUS 32 KB chunk of xe/xo.
    // Each wave stages 4 KB per tile = 4 x (64 lanes x 16 B) instructions.
    {
        const char* gA = (const char*)xe + (size_t)p0 * (DIM * 2);
        const char* gB = (const char*)xo + (size_t)k0 * (DIM * 2);
        char* lA = (char*)As;
        char* lB = (char*)Bs;
        #pragma unroll
        for (int i = 0; i < 4; ++i) {
            int Lbase = wave * 4096 + i * 1024;        // wave-uniform LDS dest
            int L = Lbase + lane * 16;                 // this lane's element
            int src = L ^ (((L >> 8) & 7) << 4);       // inverse swizzle (involution)
            gload_lds16(gA + src, lA + Lbase);
            gload_lds16(gB + src, lB + Lbase);
        }
    }
    __syncthreads();

    f32x4 acc[4][2];
    #pragma unroll
    for (int m = 0; m < 4; ++m)
        #pragma unroll
        for (int n = 0; n < 2; ++n)
            acc[m][n] = f32x4{0.f, 0.f, 0.f, 0.f};

    const int lrow = lane & 15;          // A row / B col within fragment
    const int kgrp = (lane >> 4) * 8;    // k base within fragment

    #pragma unroll
    for (int k32 = 0; k32 < 4; ++k32) {
        bf16x8 a[4], b[2];
        #pragma unroll
        for (int m = 0; m < 4; ++m) {
            int rr = wr + m * 16 + lrow;
            int idx = (rr * 128 + k32 * 32 + kgrp) ^ ((rr & 7) << 3);
            a[m] = *reinterpret_cast<const bf16x8*>(&As[idx]);
        }
        #pragma unroll
        for (int n = 0; n < 2; ++n) {
            int cc = wc + n * 16 + lrow;
            int idx = (cc * 128 + k32 * 32 + kgrp) ^ ((cc & 7) << 3);
            b[n] = *reinterpret_cast<const bf16x8*>(&Bs[idx]);
        }
        #pragma unroll
        for (int m = 0; m < 4; ++m)
            #pragma unroll
            for (int n = 0; n < 2; ++n)
                acc[m][n] = __builtin_amdgcn_mfma_f32_16x16x32_bf16(
                    a[m], b[n], acc[m][n], 0, 0, 0);
    }

    // Epilogue. C/D layout: col = lane&15, row = (lane>>4)*4 + reg (m89/m91).
    float rs[4][4];   // [m][reg j] row partials (summed over this wave's 32 cols)
    float cs[2];      // [n] col partials (summed over this wave's 64 rows)
    #pragma unroll
    for (int m = 0; m < 4; ++m)
        #pragma unroll
        for (int j = 0; j < 4; ++j) rs[m][j] = 0.0f;
    cs[0] = 0.0f; cs[1] = 0.0f;

    #pragma unroll
    for (int m = 0; m < 4; ++m)
        #pragma unroll
        for (int n = 0; n < 2; ++n)
            #pragma unroll
            for (int j = 0; j < 4; ++j) {
                float e = __expf(MARGIN_F + acc[m][n][j] * (1.0f / 128.0f));
                rs[m][j] += e;
                cs[n] += e;
            }

    // Row sums: reduce across 16 lanes of each lane-group (varying col).
    #pragma unroll
    for (int m = 0; m < 4; ++m)
        #pragma unroll
        for (int j = 0; j < 4; ++j) {
            float v = rs[m][j];
            v += __shfl_xor(v, 1);
            v += __shfl_xor(v, 2);
            v += __shfl_xor(v, 4);
            v += __shfl_xor(v, 8);
            rs[m][j] = v;
        }
    __syncthreads();   // red_r/red_c zero-init visible
    if ((lane & 15) == 0) {
        int g = lane >> 4;
        #pragma unroll
        for (int m = 0; m < 4; ++m)
            #pragma unroll
            for (int j = 0; j < 4; ++j)
                atomicAdd(&red_r[wr + m * 16 + g * 4 + j], rs[m][j]);
    }

    // Col sums: reduce across the 4 lane-groups (varying row).
    #pragma unroll
    for (int n = 0; n < 2; ++n) {
        float v = cs[n];
        v += __shfl_xor(v, 16);
        v += __shfl_xor(v, 32);
        cs[n] = v;
    }
    if (lane < 16) {
        #pragma unroll
        for (int n = 0; n < 2; ++n)
            atomicAdd(&red_c[wc + n * 16 + lane], cs[n]);
    }
    __syncthreads();

    if (tid < BT) atomicAdd(&rowsum[p0 + tid], red_r[tid]);
    else if (tid < 2 * BT) atomicAdd(&colsum[k0 + tid - BT], red_c[tid - BT]);
}

// Kernel C: per-p corrections + J + loss (fp32 exact — D_pos must stay fp32).
__global__ __launch_bounds__(256) void finalize(
    const float* __restrict__ x,
    const float* __restrict__ rowsum,
    const float* __restrict__ colsum,
    float* __restrict__ out) {

    __shared__ float wsum[4];
    const int tid = threadIdx.x;
    const int wave = tid >> 6;
    const int lane = tid & 63;
    const int p = blockIdx.x * 4 + wave;   // grid = P/4 -> p in [0,P)

    const float2* xep = reinterpret_cast<const float2*>(x + (size_t)(2 * p) * DIM);
    const float2* xop = reinterpret_cast<const float2*>(x + (size_t)(2 * p + 1) * DIM);
    float2 ve = xep[lane];
    float2 vo = xop[lane];
    float dpos = ve.x * vo.x + ve.y * vo.y;

    float ci = 0.0f, cj = 0.0f;
    if (p < P / 2) {
        const float2* xi = reinterpret_cast<const float2*>(x + (size_t)(4 * p + 3) * DIM);
        const float2* xj = reinterpret_cast<const float2*>(x + (size_t)(4 * p) * DIM);
        float2 vi = xi[lane];
        float2 vj = xj[lane];
        ci = ve.x * vi.x + ve.y * vi.y;   // dot(x[2p],   x[4p+3])
        cj = vo.x * vj.x + vo.y * vj.y;   // dot(x[2p+1], x[4p])
    }

    #pragma unroll
    for (int off = 32; off > 0; off >>= 1) {
        dpos += __shfl_down(dpos, off);
        ci   += __shfl_down(ci, off);
        cj   += __shfl_down(cj, off);
    }

    if (lane == 0) {
        float corr = 0.0f;
        if (p < P / 2)
            corr = __expf(MARGIN_F + ci * (1.0f / 128.0f))
                 + __expf(MARGIN_F + cj * (1.0f / 128.0f));
        float neg = rowsum[p] + colsum[p] - corr;
        float J = logf(EPS_F + neg) - dpos * (1.0f / 128.0f);
        float r = fmaxf(J, 0.0f);
        wsum[wave] = r * r;
    }
    __syncthreads();
    if (tid == 0) {
        float s = (wsum[0] + wsum[1] + wsum[2] + wsum[3]) * (1.0f / 8192.0f);
        atomicAdd(out, s);
    }
}

extern "C" void kernel_launch(void* const* d_in, const int* in_sizes, int n_in,
                              void* d_out, int out_size, void* d_ws, size_t ws_size,
                              hipStream_t stream) {
    const float* x = (const float*)d_in[0];
    float* rowsum = (float*)d_ws;
    float* colsum = rowsum + P;
    short* xe = (short*)(colsum + P);
    short* xo = xe + (size_t)P * DIM;

    convert_deint<<<1024, 256, 0, stream>>>(x, xe, xo, rowsum, (float*)d_out);
    dim3 grid(P / BT, P / BT);  // (32, 32)
    gram_mfma<<<grid, 512, 0, stream>>>(xe, xo, rowsum, colsum);
    finalize<<<P / 4, 256, 0, stream>>>(x, rowsum, colsum, (float*)d_out);
}

// Round 4
// 29.571 us; speedup vs baseline: 4.9181x; 1.4196x over previous
//
#include <hip/hip_runtime.h>
#include <hip/hip_bf16.h>
#include <math.h>

#define P 4096          // number of (even,odd) pairs = B/2
#define DIM 128
#define MARGIN_F 1.0f
#define EPS_F 1e-8f

#define ROWS_PER_BLOCK 64     // 4 waves x 16 rows
#define COLS_PER_BLOCK 256    // 4 tiles of 64 cols
#define TILE_COLS 64
#define NTILES 4

typedef float f32x4 __attribute__((ext_vector_type(4)));
typedef short bf16x8 __attribute__((ext_vector_type(8)));

static __device__ __forceinline__ void gload_lds16(const void* g, void* l) {
    __builtin_amdgcn_global_load_lds(
        (const __attribute__((address_space(1))) void*)g,
        (__attribute__((address_space(3))) void*)l,
        16, 0, 0);
}

// Kernel A: fp32 -> bf16 convert + deinterleave. xe is pre-scaled by 1/128
// (exact exponent shift, numerically identical to dividing the dot later).
// Also zeroes rowsum/colsum/out so no memset dispatches are needed.
__global__ __launch_bounds__(256) void convert_deint(
    const float* __restrict__ x,
    short* __restrict__ xe,      // [P][DIM] bf16 of even rows, scaled 1/128
    short* __restrict__ xo,      // [P][DIM] bf16 of odd rows
    float* __restrict__ rowcol,  // 2*P floats to zero
    float* __restrict__ out) {

    const int idx = blockIdx.x * 256 + threadIdx.x;   // 262144 float4s total
    const int row = idx >> 5;
    const int c4 = idx & 31;

    f32x4 v = *reinterpret_cast<const f32x4*>(x + (size_t)idx * 4);
    const bool odd = row & 1;
    const float s = odd ? 1.0f : 0.0078125f;   // even rows (xe) scaled 1/128
    short4 pk;
    pk.x = __builtin_bit_cast(short, __float2bfloat16(v[0] * s));
    pk.y = __builtin_bit_cast(short, __float2bfloat16(v[1] * s));
    pk.z = __builtin_bit_cast(short, __float2bfloat16(v[2] * s));
    pk.w = __builtin_bit_cast(short, __float2bfloat16(v[3] * s));
    short* dst = odd ? xo : xe;
    *reinterpret_cast<short4*>(&dst[(size_t)(row >> 1) * DIM + c4 * 4]) = pk;

    if (idx < 2 * P) rowcol[idx] = 0.0f;
    if (idx == 0) out[0] = 0.0f;
}

// Kernel B: M[p,k] = exp(1 + dot(xe_s[p], xo[k])), rowsum[p] += over k,
// colsum[k] += over p. A (64 rows x 128 k) in registers; B streamed through
// double-buffered LDS tiles (64 cols x 128 k, XOR-swizzled via pre-swizzled
// global source). Grid fully resident: 1024 blocks, 36 KB LDS -> 4 blocks/CU.
__global__ __launch_bounds__(256, 4) void gram_mfma(
    const short* __restrict__ xe,
    const short* __restrict__ xo,
    float* __restrict__ rowsum,
    float* __restrict__ colsum) {

    __shared__ __align__(16) short Bs[2][TILE_COLS * DIM];   // 2 x 16 KB
    __shared__ float cs_lds[4][COLS_PER_BLOCK];              // 4 KB

    const int tid = threadIdx.x;
    const int lane = tid & 63;
    const int wave = tid >> 6;
    const int p0 = blockIdx.y * ROWS_PER_BLOCK;
    const int c0 = blockIdx.x * COLS_PER_BLOCK;
    const int lrow = lane & 15;
    const int kgrp = (lane >> 4) * 8;   // k offset in shorts

    for (int i = tid; i < 4 * COLS_PER_BLOCK; i += 256)
        (&cs_lds[0][0])[i] = 0.0f;

    // A fragments in registers: row p0 + wave*16 + lrow, 4 k-steps.
    bf16x8 a[4];
    {
        const short* arow = xe + (size_t)(p0 + wave * 16 + lrow) * DIM + kgrp;
        #pragma unroll
        for (int k32 = 0; k32 < 4; ++k32)
            a[k32] = *reinterpret_cast<const bf16x8*>(arow + k32 * 32);
    }

    const char* gB = (const char*)(xo + (size_t)c0 * DIM);
    auto stage = [&](int t) {
        char* lB = (char*)Bs[t & 1];
        const char* gt = gB + (size_t)t * (TILE_COLS * DIM * 2);
        #pragma unroll
        for (int i = 0; i < 4; ++i) {           // 16 KB = 16 x 1 KB chunks
            int Lbase = (wave * 4 + i) * 1024;  // wave-uniform LDS dest
            int L = Lbase + lane * 16;
            int src = L ^ (((L >> 8) & 7) << 4);  // inverse swizzle (involution)
            gload_lds16(gt + src, lB + Lbase);
        }
    };
    stage(0);

    float rs[4] = {0.f, 0.f, 0.f, 0.f};   // row partials (row = w*16+g*4+j)

    for (int t = 0; t < NTILES; ++t) {
        if (t + 1 < NTILES) stage(t + 1);
        __syncthreads();   // drains vmcnt -> tile t (and t+1) staged

        const short* B = Bs[t & 1];
        f32x4 acc[4];
        #pragma unroll
        for (int n = 0; n < 4; ++n) acc[n] = f32x4{0.f, 0.f, 0.f, 0.f};

        #pragma unroll
        for (int k32 = 0; k32 < 4; ++k32) {
            #pragma unroll
            for (int n = 0; n < 4; ++n) {
                int cc = n * 16 + lrow;
                int idx = (cc * DIM + k32 * 32 + kgrp) ^ ((cc & 7) << 3);
                bf16x8 b = *reinterpret_cast<const bf16x8*>(&B[idx]);
                acc[n] = __builtin_amdgcn_mfma_f32_16x16x32_bf16(
                    a[k32], b, acc[n], 0, 0, 0);
            }
        }

        // Epilogue: exp, accumulate row partials in regs, col partials in LDS.
        // C/D layout: col = lane&15, row = (lane>>4)*4 + j (m89/m91).
        #pragma unroll
        for (int n = 0; n < 4; ++n) {
            float cp = 0.0f;
            #pragma unroll
            for (int j = 0; j < 4; ++j) {
                float e = __expf(MARGIN_F + acc[n][j]);
                rs[j] += e;
                cp += e;
            }
            cp += __shfl_xor(cp, 16);   // sum over the wave's 4 row-groups
            cp += __shfl_xor(cp, 32);
            if (lane < 16)
                cs_lds[wave][t * TILE_COLS + n * 16 + lane] += cp;
        }
        __syncthreads();   // Bs[t&1] free for stage(t+2); cs_lds ordered
    }

    // Row sums: reduce across the 16 col-lanes of each lane-group.
    #pragma unroll
    for (int j = 0; j < 4; ++j) {
        float v = rs[j];
        v += __shfl_xor(v, 1);
        v += __shfl_xor(v, 2);
        v += __shfl_xor(v, 4);
        v += __shfl_xor(v, 8);
        rs[j] = v;
    }
    if (lrow == 0) {
        int g = lane >> 4;
        #pragma unroll
        for (int j = 0; j < 4; ++j)
            atomicAdd(&rowsum[p0 + wave * 16 + g * 4 + j], rs[j]);
    }

    // Col sums: combine the 4 per-wave partials, one atomic per col.
    float s = cs_lds[0][tid] + cs_lds[1][tid] + cs_lds[2][tid] + cs_lds[3][tid];
    atomicAdd(&colsum[c0 + tid], s);
}

// Kernel C: per-p corrections + J + loss (fp32 exact). 16 pairs per block.
__global__ __launch_bounds__(256) void finalize(
    const float* __restrict__ x,
    const float* __restrict__ rowsum,
    const float* __restrict__ colsum,
    float* __restrict__ out) {

    __shared__ float wsum[4];
    const int tid = threadIdx.x;
    const int wave = tid >> 6;
    const int lane = tid & 63;

    float racc = 0.0f;
    #pragma unroll
    for (int q = 0; q < 4; ++q) {
        const int p = blockIdx.x * 16 + wave * 4 + q;

        const float2* xep = reinterpret_cast<const float2*>(x + (size_t)(2 * p) * DIM);
        const float2* xop = reinterpret_cast<const float2*>(x + (size_t)(2 * p + 1) * DIM);
        float2 ve = xep[lane];
        float2 vo = xop[lane];
        float dpos = ve.x * vo.x + ve.y * vo.y;

        float ci = 0.0f, cj = 0.0f;
        if (p < P / 2) {
            const float2* xi = reinterpret_cast<const float2*>(x + (size_t)(4 * p + 3) * DIM);
            const float2* xj = reinterpret_cast<const float2*>(x + (size_t)(4 * p) * DIM);
            float2 vi = xi[lane];
            float2 vj = xj[lane];
            ci = ve.x * vi.x + ve.y * vi.y;   // dot(x[2p],   x[4p+3])
            cj = vo.x * vj.x + vo.y * vj.y;   // dot(x[2p+1], x[4p])
        }

        #pragma unroll
        for (int off = 32; off > 0; off >>= 1) {
            dpos += __shfl_down(dpos, off);
            ci   += __shfl_down(ci, off);
            cj   += __shfl_down(cj, off);
        }

        if (lane == 0) {
            float corr = 0.0f;
            if (p < P / 2)
                corr = __expf(MARGIN_F + ci * (1.0f / 128.0f))
                     + __expf(MARGIN_F + cj * (1.0f / 128.0f));
            float neg = rowsum[p] + colsum[p] - corr;
            float J = logf(EPS_F + neg) - dpos * (1.0f / 128.0f);
            float r = fmaxf(J, 0.0f);
            racc += r * r;
        }
    }

    if (lane == 0) wsum[wave] = racc;
    __syncthreads();
    if (tid == 0) {
        float s = (wsum[0] + wsum[1] + wsum[2] + wsum[3]) * (1.0f / 8192.0f);
        atomicAdd(out, s);
    }
}

extern "C" void kernel_launch(void* const* d_in, const int* in_sizes, int n_in,
                              void* d_out, int out_size, void* d_ws, size_t ws_size,
                              hipStream_t stream) {
    const float* x = (const float*)d_in[0];
    float* rowsum = (float*)d_ws;
    float* colsum = rowsum + P;
    short* xe = (short*)(colsum + P);
    short* xo = xe + (size_t)P * DIM;

    convert_deint<<<1024, 256, 0, stream>>>(x, xe, xo, rowsum, (float*)d_out);
    dim3 grid(P / COLS_PER_BLOCK, P / ROWS_PER_BLOCK);  // (16, 64)
    gram_mfma<<<grid, 256, 0, stream>>>(xe, xo, rowsum, colsum);
    finalize<<<P / 16, 256, 0, stream>>>(x, rowsum, colsum, (float*)d_out);
}

// Round 5
// 29.408 us; speedup vs baseline: 4.9452x; 1.0055x over previous
//
#include <hip/hip_runtime.h>
#include <hip/hip_bf16.h>
#include <math.h>

#define P 4096          // number of (even,odd) pairs = B/2
#define DIM 128
#define MARGIN_F 1.0f
#define EPS_F 1e-8f

#define ROWS_PER_BLOCK 64     // 4 waves x 16 rows
#define COLS_PER_BLOCK 256    // 4 tiles of 64 cols
#define TILE_COLS 64
#define NTILES 4

typedef float f32x4 __attribute__((ext_vector_type(4)));
typedef short bf16x8 __attribute__((ext_vector_type(8)));

static __device__ __forceinline__ void gload_lds16(const void* g, void* l) {
    __builtin_amdgcn_global_load_lds(
        (const __attribute__((address_space(1))) void*)g,
        (__attribute__((address_space(3))) void*)l,
        16, 0, 0);
}

// Kernel A: fp32 -> bf16 convert + deinterleave. xe is pre-scaled by 1/128
// (exact exponent shift). Also zeroes rowsum/colsum/out.
__global__ __launch_bounds__(256) void convert_deint(
    const float* __restrict__ x,
    short* __restrict__ xe,      // [P][DIM] bf16 of even rows, scaled 1/128
    short* __restrict__ xo,      // [P][DIM] bf16 of odd rows
    float* __restrict__ rowcol,  // 2*P floats to zero
    float* __restrict__ out) {

    const int idx = blockIdx.x * 256 + threadIdx.x;   // 262144 float4s total
    const int row = idx >> 5;
    const int c4 = idx & 31;

    f32x4 v = *reinterpret_cast<const f32x4*>(x + (size_t)idx * 4);
    const bool odd = row & 1;
    const float s = odd ? 1.0f : 0.0078125f;   // even rows (xe) scaled 1/128
    short4 pk;
    pk.x = __builtin_bit_cast(short, __float2bfloat16(v[0] * s));
    pk.y = __builtin_bit_cast(short, __float2bfloat16(v[1] * s));
    pk.z = __builtin_bit_cast(short, __float2bfloat16(v[2] * s));
    pk.w = __builtin_bit_cast(short, __float2bfloat16(v[3] * s));
    short* dst = odd ? xo : xe;
    *reinterpret_cast<short4*>(&dst[(size_t)(row >> 1) * DIM + c4 * 4]) = pk;

    if (idx < 2 * P) rowcol[idx] = 0.0f;
    if (idx == 0) out[0] = 0.0f;
}

// Kernel B: M[p,k] = exp(1 + dot(xe_s[p], xo[k])), rowsum[p] += over k,
// colsum[k] += over p. A (64x128) in registers; B double-buffered in LDS with
// a proper 2-phase pipeline: ONE barrier per tile, stage(t+1) in flight
// across compute(t) (ds_reads wait lgkmcnt only; vmcnt drains at the barrier).
__global__ __launch_bounds__(256, 4) void gram_mfma(
    const short* __restrict__ xe,
    const short* __restrict__ xo,
    float* __restrict__ rowsum,
    float* __restrict__ colsum) {

    __shared__ __align__(16) short Bs[2][TILE_COLS * DIM];   // 2 x 16 KB
    __shared__ float cs_lds[4][COLS_PER_BLOCK];              // 4 KB

    const int tid = threadIdx.x;
    const int lane = tid & 63;
    const int wave = tid >> 6;
    const int p0 = blockIdx.y * ROWS_PER_BLOCK;
    const int c0 = blockIdx.x * COLS_PER_BLOCK;
    const int lrow = lane & 15;
    const int kgrp = (lane >> 4) * 8;   // k offset in shorts

    for (int i = tid; i < 4 * COLS_PER_BLOCK; i += 256)
        (&cs_lds[0][0])[i] = 0.0f;

    const char* gB = (const char*)(xo + (size_t)c0 * DIM);
    auto stage = [&](int t) {
        char* lB = (char*)Bs[t & 1];
        const char* gt = gB + (size_t)t * (TILE_COLS * DIM * 2);
        #pragma unroll
        for (int i = 0; i < 4; ++i) {           // 16 KB = 16 x 1 KB chunks
            int Lbase = (wave * 4 + i) * 1024;  // wave-uniform LDS dest
            int L = Lbase + lane * 16;
            int src = L ^ (((L >> 8) & 7) << 4);  // inverse swizzle (involution)
            gload_lds16(gt + src, lB + Lbase);
        }
    };
    stage(0);

    // A fragments in registers: row p0 + wave*16 + lrow, 4 k-steps.
    // Issued after stage(0) so the gload_lds goes out first.
    bf16x8 a[4];
    {
        const short* arow = xe + (size_t)(p0 + wave * 16 + lrow) * DIM + kgrp;
        #pragma unroll
        for (int k32 = 0; k32 < 4; ++k32)
            a[k32] = *reinterpret_cast<const bf16x8*>(arow + k32 * 32);
    }

    float rs[4] = {0.f, 0.f, 0.f, 0.f};   // row partials (row = w*16+g*4+j)

    for (int t = 0; t < NTILES; ++t) {
        // Barrier: (a) vmcnt(0) -> stage(t) landed; (b) all waves finished
        // compute(t-1), so Bs[(t+1)&1] is safe to overwrite.
        __syncthreads();
        if (t + 1 < NTILES) stage(t + 1);   // stays in flight across compute(t)

        const short* B = Bs[t & 1];
        f32x4 acc[4];
        #pragma unroll
        for (int n = 0; n < 4; ++n) acc[n] = f32x4{0.f, 0.f, 0.f, 0.f};

        #pragma unroll
        for (int k32 = 0; k32 < 4; ++k32) {
            #pragma unroll
            for (int n = 0; n < 4; ++n) {
                int cc = n * 16 + lrow;
                int idx = (cc * DIM + k32 * 32 + kgrp) ^ ((cc & 7) << 3);
                bf16x8 b = *reinterpret_cast<const bf16x8*>(&B[idx]);
                acc[n] = __builtin_amdgcn_mfma_f32_16x16x32_bf16(
                    a[k32], b, acc[n], 0, 0, 0);
            }
        }

        // Epilogue: exp, row partials in regs, col partials in per-wave LDS
        // slots (no cross-wave race -> no barrier needed here).
        // C/D layout: col = lane&15, row = (lane>>4)*4 + j (m89/m91).
        #pragma unroll
        for (int n = 0; n < 4; ++n) {
            float cp = 0.0f;
            #pragma unroll
            for (int j = 0; j < 4; ++j) {
                float e = __expf(MARGIN_F + acc[n][j]);
                rs[j] += e;
                cp += e;
            }
            cp += __shfl_xor(cp, 16);   // sum over the wave's 4 row-groups
            cp += __shfl_xor(cp, 32);
            if (lane < 16)
                cs_lds[wave][t * TILE_COLS + n * 16 + lane] += cp;
        }
    }

    // Row sums: reduce across the 16 col-lanes of each lane-group.
    #pragma unroll
    for (int j = 0; j < 4; ++j) {
        float v = rs[j];
        v += __shfl_xor(v, 1);
        v += __shfl_xor(v, 2);
        v += __shfl_xor(v, 4);
        v += __shfl_xor(v, 8);
        rs[j] = v;
    }
    if (lrow == 0) {
        int g = lane >> 4;
        #pragma unroll
        for (int j = 0; j < 4; ++j)
            atomicAdd(&rowsum[p0 + wave * 16 + g * 4 + j], rs[j]);
    }

    __syncthreads();   // cs_lds complete across waves
    // Col sums: combine the 4 per-wave partials, one atomic per col.
    float s = cs_lds[0][tid] + cs_lds[1][tid] + cs_lds[2][tid] + cs_lds[3][tid];
    atomicAdd(&colsum[c0 + tid], s);
}

// Kernel C: per-p corrections + J + loss (fp32 exact). 16 pairs per block.
__global__ __launch_bounds__(256) void finalize(
    const float* __restrict__ x,
    const float* __restrict__ rowsum,
    const float* __restrict__ colsum,
    float* __restrict__ out) {

    __shared__ float wsum[4];
    const int tid = threadIdx.x;
    const int wave = tid >> 6;
    const int lane = tid & 63;

    float racc = 0.0f;
    #pragma unroll
    for (int q = 0; q < 4; ++q) {
        const int p = blockIdx.x * 16 + wave * 4 + q;

        const float2* xep = reinterpret_cast<const float2*>(x + (size_t)(2 * p) * DIM);
        const float2* xop = reinterpret_cast<const float2*>(x + (size_t)(2 * p + 1) * DIM);
        float2 ve = xep[lane];
        float2 vo = xop[lane];
        float dpos = ve.x * vo.x + ve.y * vo.y;

        float ci = 0.0f, cj = 0.0f;
        if (p < P / 2) {
            const float2* xi = reinterpret_cast<const float2*>(x + (size_t)(4 * p + 3) * DIM);
            const float2* xj = reinterpret_cast<const float2*>(x + (size_t)(4 * p) * DIM);
            float2 vi = xi[lane];
            float2 vj = xj[lane];
            ci = ve.x * vi.x + ve.y * vi.y;   // dot(x[2p],   x[4p+3])
            cj = vo.x * vj.x + vo.y * vj.y;   // dot(x[2p+1], x[4p])
        }

        #pragma unroll
        for (int off = 32; off > 0; off >>= 1) {
            dpos += __shfl_down(dpos, off);
            ci   += __shfl_down(ci, off);
            cj   += __shfl_down(cj, off);
        }

        if (lane == 0) {
            float corr = 0.0f;
            if (p < P / 2)
                corr = __expf(MARGIN_F + ci * (1.0f / 128.0f))
                     + __expf(MARGIN_F + cj * (1.0f / 128.0f));
            float neg = rowsum[p] + colsum[p] - corr;
            float J = logf(EPS_F + neg) - dpos * (1.0f / 128.0f);
            float r = fmaxf(J, 0.0f);
            racc += r * r;
        }
    }

    if (lane == 0) wsum[wave] = racc;
    __syncthreads();
    if (tid == 0) {
        float s = (wsum[0] + wsum[1] + wsum[2] + wsum[3]) * (1.0f / 8192.0f);
        atomicAdd(out, s);
    }
}

extern "C" void kernel_launch(void* const* d_in, const int* in_sizes, int n_in,
                              void* d_out, int out_size, void* d_ws, size_t ws_size,
                              hipStream_t stream) {
    const float* x = (const float*)d_in[0];
    float* rowsum = (float*)d_ws;
    float* colsum = rowsum + P;
    short* xe = (short*)(colsum + P);
    short* xo = xe + (size_t)P * DIM;

    convert_deint<<<1024, 256, 0, stream>>>(x, xe, xo, rowsum, (float*)d_out);
    dim3 grid(P / COLS_PER_BLOCK, P / ROWS_PER_BLOCK);  // (16, 64)
    gram_mfma<<<grid, 256, 0, stream>>>(xe, xo, rowsum, colsum);
    finalize<<<P / 16, 256, 0, stream>>>(x, rowsum, colsum, (float*)d_out);
}

// Round 6
// 28.698 us; speedup vs baseline: 5.0676x; 1.0247x over previous
//
#include <hip/hip_runtime.h>
#include <hip/hip_bf16.h>
#include <math.h>

#define P 4096          // number of (even,odd) pairs = B/2
#define DIM 128
#define MARGIN_F 1.0f
#define EPS_F 1e-8f

#define ROWS_PER_BLOCK 128    // 4 waves x 32 rows
#define COLS_PER_BLOCK 256    // 4 tiles of 64 cols
#define TILE_COLS 64
#define NTILES 4

typedef float f32x4 __attribute__((ext_vector_type(4)));
typedef short bf16x8 __attribute__((ext_vector_type(8)));

static __device__ __forceinline__ void gload_lds16(const void* g, void* l) {
    __builtin_amdgcn_global_load_lds(
        (const __attribute__((address_space(1))) void*)g,
        (__attribute__((address_space(3))) void*)l,
        16, 0, 0);
}

// Kernel A: fp32 -> bf16 convert + deinterleave. xe is pre-scaled by 1/128
// (exact exponent shift). Also zeroes rowsum/colsum/out.
__global__ __launch_bounds__(256) void convert_deint(
    const float* __restrict__ x,
    short* __restrict__ xe,      // [P][DIM] bf16 of even rows, scaled 1/128
    short* __restrict__ xo,      // [P][DIM] bf16 of odd rows
    float* __restrict__ rowcol,  // 2*P floats to zero
    float* __restrict__ out) {

    const int idx = blockIdx.x * 256 + threadIdx.x;   // 262144 float4s total
    const int row = idx >> 5;
    const int c4 = idx & 31;

    f32x4 v = *reinterpret_cast<const f32x4*>(x + (size_t)idx * 4);
    const bool odd = row & 1;
    const float s = odd ? 1.0f : 0.0078125f;   // even rows (xe) scaled 1/128
    short4 pk;
    pk.x = __builtin_bit_cast(short, __float2bfloat16(v[0] * s));
    pk.y = __builtin_bit_cast(short, __float2bfloat16(v[1] * s));
    pk.z = __builtin_bit_cast(short, __float2bfloat16(v[2] * s));
    pk.w = __builtin_bit_cast(short, __float2bfloat16(v[3] * s));
    short* dst = odd ? xo : xe;
    *reinterpret_cast<short4*>(&dst[(size_t)(row >> 1) * DIM + c4 * 4]) = pk;

    if (idx < 2 * P) rowcol[idx] = 0.0f;
    if (idx == 0) out[0] = 0.0f;
}

// Kernel B: M[p,k] = exp(1 + dot(xe_s[p], xo[k])), rowsum[p] += over k,
// colsum[k] += over p. 128 rows/block (32 rows/wave -> each B-fragment read
// feeds 2 MFMAs, halving LDS fragment traffic). Col partials in registers
// (t-loop unrolled, static indexing); one shfl-reduce + atomics at exit.
__global__ __launch_bounds__(256, 2) void gram_mfma(
    const short* __restrict__ xe,
    const short* __restrict__ xo,
    float* __restrict__ rowsum,
    float* __restrict__ colsum) {

    __shared__ __align__(16) short Bs[2][TILE_COLS * DIM];   // 2 x 16 KB

    const int tid = threadIdx.x;
    const int lane = tid & 63;
    const int wave = tid >> 6;
    const int p0 = blockIdx.y * ROWS_PER_BLOCK;
    const int c0 = blockIdx.x * COLS_PER_BLOCK;
    const int lrow = lane & 15;
    const int kgrp = (lane >> 4) * 8;   // k offset in shorts

    const char* gB = (const char*)(xo + (size_t)c0 * DIM);
    auto stage = [&](int t) {
        char* lB = (char*)Bs[t & 1];
        const char* gt = gB + (size_t)t * (TILE_COLS * DIM * 2);
        #pragma unroll
        for (int i = 0; i < 4; ++i) {           // 16 KB = 16 x 1 KB chunks
            int Lbase = (wave * 4 + i) * 1024;  // wave-uniform LDS dest
            int L = Lbase + lane * 16;
            int src = L ^ (((L >> 8) & 7) << 4);  // inverse swizzle (involution)
            gload_lds16(gt + src, lB + Lbase);
        }
    };
    stage(0);

    // A fragments in registers: rows p0 + wave*32 + m*16 + lrow, 4 k-steps.
    bf16x8 a[2][4];
    #pragma unroll
    for (int m = 0; m < 2; ++m) {
        const short* arow =
            xe + (size_t)(p0 + wave * 32 + m * 16 + lrow) * DIM + kgrp;
        #pragma unroll
        for (int k32 = 0; k32 < 4; ++k32)
            a[m][k32] = *reinterpret_cast<const bf16x8*>(arow + k32 * 32);
    }

    float rs[2][4];        // row partials [m][j], row = w*32+m*16+g*4+j
    float cpp[NTILES][4];  // col partials [t][n] (static idx via unroll)
    #pragma unroll
    for (int m = 0; m < 2; ++m)
        #pragma unroll
        for (int j = 0; j < 4; ++j) rs[m][j] = 0.0f;
    #pragma unroll
    for (int t = 0; t < NTILES; ++t)
        #pragma unroll
        for (int n = 0; n < 4; ++n) cpp[t][n] = 0.0f;

    #pragma unroll
    for (int t = 0; t < NTILES; ++t) {
        // Barrier: (a) vmcnt drains -> stage(t) landed; (b) all waves done
        // with compute(t-1), so Bs[(t+1)&1] is safe to overwrite.
        __syncthreads();
        if (t + 1 < NTILES) stage(t + 1);   // in flight across compute(t)

        const short* B = Bs[t & 1];
        f32x4 acc[2][4];
        #pragma unroll
        for (int m = 0; m < 2; ++m)
            #pragma unroll
            for (int n = 0; n < 4; ++n) acc[m][n] = f32x4{0.f, 0.f, 0.f, 0.f};

        #pragma unroll
        for (int k32 = 0; k32 < 4; ++k32) {
            #pragma unroll
            for (int n = 0; n < 4; ++n) {
                int cc = n * 16 + lrow;
                int idx = (cc * DIM + k32 * 32 + kgrp) ^ ((cc & 7) << 3);
                bf16x8 b = *reinterpret_cast<const bf16x8*>(&B[idx]);
                #pragma unroll
                for (int m = 0; m < 2; ++m)
                    acc[m][n] = __builtin_amdgcn_mfma_f32_16x16x32_bf16(
                        a[m][k32], b, acc[m][n], 0, 0, 0);
            }
        }

        // Epilogue: exp, all partials in registers.
        // C/D layout: col = lane&15, row = (lane>>4)*4 + j (m89/m91).
        #pragma unroll
        for (int n = 0; n < 4; ++n)
            #pragma unroll
            for (int m = 0; m < 2; ++m)
                #pragma unroll
                for (int j = 0; j < 4; ++j) {
                    float e = __expf(MARGIN_F + acc[m][n][j]);
                    rs[m][j] += e;
                    cpp[t][n] += e;
                }
    }

    // Row sums: reduce across the 16 col-lanes of each lane-group.
    #pragma unroll
    for (int m = 0; m < 2; ++m)
        #pragma unroll
        for (int j = 0; j < 4; ++j) {
            float v = rs[m][j];
            v += __shfl_xor(v, 1);
            v += __shfl_xor(v, 2);
            v += __shfl_xor(v, 4);
            v += __shfl_xor(v, 8);
            rs[m][j] = v;
        }
    if (lrow == 0) {
        int g = lane >> 4;
        #pragma unroll
        for (int m = 0; m < 2; ++m)
            #pragma unroll
            for (int j = 0; j < 4; ++j)
                atomicAdd(&rowsum[p0 + wave * 32 + m * 16 + g * 4 + j],
                          rs[m][j]);
    }

    // Col sums: reduce across the 4 row-groups, one atomic per col per wave.
    #pragma unroll
    for (int t = 0; t < NTILES; ++t)
        #pragma unroll
        for (int n = 0; n < 4; ++n) {
            float v = cpp[t][n];
            v += __shfl_xor(v, 16);
            v += __shfl_xor(v, 32);
            if (lane < 16)
                atomicAdd(&colsum[c0 + t * TILE_COLS + n * 16 + lane], v);
        }
}

// Kernel C: per-p corrections + J + loss (fp32 exact). 16 pairs per block.
__global__ __launch_bounds__(256) void finalize(
    const float* __restrict__ x,
    const float* __restrict__ rowsum,
    const float* __restrict__ colsum,
    float* __restrict__ out) {

    __shared__ float wsum[4];
    const int tid = threadIdx.x;
    const int wave = tid >> 6;
    const int lane = tid & 63;

    float racc = 0.0f;
    #pragma unroll
    for (int q = 0; q < 4; ++q) {
        const int p = blockIdx.x * 16 + wave * 4 + q;

        const float2* xep = reinterpret_cast<const float2*>(x + (size_t)(2 * p) * DIM);
        const float2* xop = reinterpret_cast<const float2*>(x + (size_t)(2 * p + 1) * DIM);
        float2 ve = xep[lane];
        float2 vo = xop[lane];
        float dpos = ve.x * vo.x + ve.y * vo.y;

        float ci = 0.0f, cj = 0.0f;
        if (p < P / 2) {
            const float2* xi = reinterpret_cast<const float2*>(x + (size_t)(4 * p + 3) * DIM);
            const float2* xj = reinterpret_cast<const float2*>(x + (size_t)(4 * p) * DIM);
            float2 vi = xi[lane];
            float2 vj = xj[lane];
            ci = ve.x * vi.x + ve.y * vi.y;   // dot(x[2p],   x[4p+3])
            cj = vo.x * vj.x + vo.y * vj.y;   // dot(x[2p+1], x[4p])
        }

        #pragma unroll
        for (int off = 32; off > 0; off >>= 1) {
            dpos += __shfl_down(dpos, off);
            ci   += __shfl_down(ci, off);
            cj   += __shfl_down(cj, off);
        }

        if (lane == 0) {
            float corr = 0.0f;
            if (p < P / 2)
                corr = __expf(MARGIN_F + ci * (1.0f / 128.0f))
                     + __expf(MARGIN_F + cj * (1.0f / 128.0f));
            float neg = rowsum[p] + colsum[p] - corr;
            float J = logf(EPS_F + neg) - dpos * (1.0f / 128.0f);
            float r = fmaxf(J, 0.0f);
            racc += r * r;
        }
    }

    if (lane == 0) wsum[wave] = racc;
    __syncthreads();
    if (tid == 0) {
        float s = (wsum[0] + wsum[1] + wsum[2] + wsum[3]) * (1.0f / 8192.0f);
        atomicAdd(out, s);
    }
}

extern "C" void kernel_launch(void* const* d_in, const int* in_sizes, int n_in,
                              void* d_out, int out_size, void* d_ws, size_t ws_size,
                              hipStream_t stream) {
    const float* x = (const float*)d_in[0];
    float* rowsum = (float*)d_ws;
    float* colsum = rowsum + P;
    short* xe = (short*)(colsum + P);
    short* xo = xe + (size_t)P * DIM;

    convert_deint<<<1024, 256, 0, stream>>>(x, xe, xo, rowsum, (float*)d_out);
    dim3 grid(P / COLS_PER_BLOCK, P / ROWS_PER_BLOCK);  // (16, 32)
    gram_mfma<<<grid, 256, 0, stream>>>(xe, xo, rowsum, colsum);
    finalize<<<P / 16, 256, 0, stream>>>(x, rowsum, colsum, (float*)d_out);
}